// Round 1
// baseline (374.067 us; speedup 1.0000x reference)
//
#include <hip/hip_runtime.h>

// Problem constants (fixed shapes from setup_inputs)
#define HH 540
#define WW 960
#define NC 3
#define ND 60          // disparities 1..60
#define NP (HH * WW)   // 518400 pixels per plane
#define STRIP 45       // rows per block in cost kernel (540 = 12*45)
#define OUTC 248       // output columns per col-block (4 blocks * 248 >= 960)

// ---------------------------------------------------------------------------
// Kernel 1: channel-summed horizontal 9-window sums (zero padding on x)
//   hsL(y,x)  = sum_{dx=-4..4} sum_c L[c,y,x+dx]
//   hsLL      = same with L^2;  hsR, hsRR for R.
// ---------------------------------------------------------------------------
__global__ __launch_bounds__(256) void k_stats_h(
    const float* __restrict__ L, const float* __restrict__ R,
    float* __restrict__ hsL, float* __restrict__ hsLL,
    float* __restrict__ hsR, float* __restrict__ hsRR) {
    int x = blockIdx.x * blockDim.x + threadIdx.x;
    int y = blockIdx.y;
    if (x >= WW) return;
    float a = 0.f, a2 = 0.f, b = 0.f, b2 = 0.f;
#pragma unroll
    for (int dx = -4; dx <= 4; ++dx) {
        int xx = x + dx;
        if (xx < 0 || xx >= WW) continue;
#pragma unroll
        for (int c = 0; c < NC; ++c) {
            float l = L[(c * HH + y) * WW + xx];
            float r = R[(c * HH + y) * WW + xx];
            a += l; a2 = fmaf(l, l, a2);
            b += r; b2 = fmaf(r, r, b2);
        }
    }
    int o = y * WW + x;
    hsL[o] = a; hsLL[o] = a2; hsR[o] = b; hsRR[o] = b2;
}

// ---------------------------------------------------------------------------
// Kernel 2: vertical 9-window sums (zero padding on y) + finalize stats:
//   LSum, sqrtL = sqrt(L2Sum - LSum^2/n + 1e-5), RSum/n, sqrtR
// ---------------------------------------------------------------------------
__global__ __launch_bounds__(256) void k_stats_v(
    const float* __restrict__ hsL, const float* __restrict__ hsLL,
    const float* __restrict__ hsR, const float* __restrict__ hsRR,
    float* __restrict__ LSum, float* __restrict__ sqLa,
    float* __restrict__ RSn, float* __restrict__ sqRa) {
    int x = blockIdx.x * blockDim.x + threadIdx.x;
    int y = blockIdx.y;
    if (x >= WW) return;
    float a = 0.f, a2 = 0.f, b = 0.f, b2 = 0.f;
#pragma unroll
    for (int dy = -4; dy <= 4; ++dy) {
        int yy = y + dy;
        if (yy < 0 || yy >= HH) continue;
        int o = yy * WW + x;
        a += hsL[o]; a2 += hsLL[o]; b += hsR[o]; b2 += hsRR[o];
    }
    const float inv_n = 1.0f / 243.0f;
    int o = y * WW + x;
    LSum[o] = a;
    sqLa[o] = sqrtf(fmaf(-a * inv_n, a, a2) + 1e-5f);
    RSn[o]  = b * inv_n;
    sqRa[o] = sqrtf(fmaf(-b * inv_n, b, b2) + 1e-5f);
}

// ---------------------------------------------------------------------------
// Q(y,x) = sum_c L[c,y,x] * R[c,y,x-d]   (caller guarantees x in [d, W))
// Zero outside the image vertically.
// ---------------------------------------------------------------------------
__device__ __forceinline__ float qval(const float* __restrict__ L,
                                      const float* __restrict__ R,
                                      int yy, int xq, int d) {
    if ((unsigned)yy >= (unsigned)HH) return 0.f;
    int o = yy * WW + xq;
    float q = L[o] * R[o - d];
    q = fmaf(L[o + NP], R[o - d + NP], q);
    q = fmaf(L[o + 2 * NP], R[o - d + 2 * NP], q);
    return q;
}

// ---------------------------------------------------------------------------
// Kernel 3: main cost kernel.
// Grid: (4 col-blocks, 12 row-strips, 60 disparities). 256 threads.
// Thread t owns column xq = x0 - 4 + t (4-col halo each side).
// Maintains vertical sliding 9-sum of Q in a register; horizontal 9-sum
// via LDS. Writes costL[d,y,x] and costR[d,y,x-d] (identical value — proven
// equivalence), plus the zero regions.
// ---------------------------------------------------------------------------
__global__ __launch_bounds__(256) void k_cost(
    const float* __restrict__ L, const float* __restrict__ R,
    const float* __restrict__ LSum, const float* __restrict__ sqLa,
    const float* __restrict__ RSn, const float* __restrict__ sqRa,
    float* __restrict__ out) {
    __shared__ float vbuf[256];
    const int t  = threadIdx.x;
    const int d  = blockIdx.z + 1;             // disparity 1..60
    const int y0 = blockIdx.y * STRIP;
    const int x0 = blockIdx.x * OUTC;
    const int xq = x0 - 4 + t;

    const bool qvalid = (xq >= d) && (xq < WW);

    // init vertical sliding sum over rows [y0-4, y0+4]
    float v = 0.f;
    if (qvalid) {
#pragma unroll
        for (int dy = -4; dy <= 4; ++dy) v += qval(L, R, y0 + dy, xq, d);
    }

    float* outL = out + (size_t)(d - 1) * NP;
    float* outR = out + (size_t)ND * NP + (size_t)(d - 1) * NP;
    const bool isOut = (t >= 4) && (t < 4 + OUTC) && (xq < WW);

    for (int y = y0; y < y0 + STRIP; ++y) {
        vbuf[t] = v;
        __syncthreads();
        if (isOut) {
            float cross = 0.f;
#pragma unroll
            for (int j = -4; j <= 4; ++j) cross += vbuf[t + j];
            const int x = xq;
            const int o = y * WW + x;
            float cl = 0.f;
            if (x >= d) {
                float num = fmaf(-LSum[o], RSn[o - d], cross) + 1e-6f;
                float den = fmaf(sqLa[o], sqRa[o - d], 1e-6f);
                cl = num * __builtin_amdgcn_rcpf(den);
                outR[o - d] = cl;              // costR(d, y, x-d) == costL(d, y, x)
            }
            outL[o] = cl;                      // zero for x < d
            if (x >= WW - d) outR[o] = 0.f;    // costR right-edge zero region
        }
        __syncthreads();
        // slide window: rows [y-4, y+4] -> [y-3, y+5]
        if (qvalid) {
            v += qval(L, R, y + 5, xq, d) - qval(L, R, y - 4, xq, d);
        }
    }
}

// ---------------------------------------------------------------------------
extern "C" void kernel_launch(void* const* d_in, const int* in_sizes, int n_in,
                              void* d_out, int out_size, void* d_ws, size_t ws_size,
                              hipStream_t stream) {
    const float* L = (const float*)d_in[0];
    const float* R = (const float*)d_in[1];
    float* out = (float*)d_out;
    float* ws = (float*)d_ws;

    float* hsL  = ws + 0 * (size_t)NP;
    float* hsLL = ws + 1 * (size_t)NP;
    float* hsR  = ws + 2 * (size_t)NP;
    float* hsRR = ws + 3 * (size_t)NP;
    float* LSum = ws + 4 * (size_t)NP;
    float* sqLa = ws + 5 * (size_t)NP;
    float* RSn  = ws + 6 * (size_t)NP;
    float* sqRa = ws + 7 * (size_t)NP;

    dim3 blk(256);
    dim3 g1((WW + 255) / 256, HH);
    k_stats_h<<<g1, blk, 0, stream>>>(L, R, hsL, hsLL, hsR, hsRR);
    k_stats_v<<<g1, blk, 0, stream>>>(hsL, hsLL, hsR, hsRR, LSum, sqLa, RSn, sqRa);

    dim3 g3((WW + OUTC - 1) / OUTC, HH / STRIP, ND);
    k_cost<<<g3, blk, 0, stream>>>(L, R, LSum, sqLa, RSn, sqRa, out);
}